// Round 14
// baseline (116.658 us; speedup 1.0000x reference)
//
#include <hip/hip_runtime.h>
#include <math.h>

#ifndef NSWEEP
#define NSWEEP 4   // HARD MINIMUM (R12 measured): 3 sweeps -> absmax 0.14 FAIL,
                   // 4 sweeps -> 0.0156 pass (bf16-quantization floor, 3x margin).
#endif

#define EPSV 1e-8f
#define BT 256       // threads per block
#define NM 3         // matrices per thread, SoA-forced (f3)
#define MPB (NM * BT)

__device__ __forceinline__ float fast_rsqf(float x) {
#if __has_builtin(__builtin_amdgcn_rsqf)
  return __builtin_amdgcn_rsqf(x);
#else
  return rsqrtf(x);
#endif
}
__device__ __forceinline__ float fast_logf(float x) {
#if __has_builtin(__builtin_amdgcn_logf)
  return __builtin_amdgcn_logf(x) * 0.6931471805599453f;  // v_log_f32 is log2
#else
  return logf(x);
#endif
}

// f3 = three independent matrices' scalars, forced instruction-tripling.
// Same mechanism as R11's f2 (HW-verified): SoA packing means the scheduler
// cannot reduce peak pressure by serializing, so the interleave survives
// codegen. State 26x3=78 floats + ~20 temps ~= 100 VGPR < 128 cap of
// __launch_bounds__(256,4). (f4 would be ~130 -> spill risk; not taken.)
struct f3 { float x, y, z; };
__device__ __forceinline__ f3 F3(float a, float b, float c) {
  f3 r; r.x = a; r.y = b; r.z = c; return r;
}
__device__ __forceinline__ f3 f3rep(float a) { return F3(a, a, a); }
__device__ __forceinline__ f3 f3add(f3 a, f3 b) { return F3(a.x + b.x, a.y + b.y, a.z + b.z); }
__device__ __forceinline__ f3 f3sub(f3 a, f3 b) { return F3(a.x - b.x, a.y - b.y, a.z - b.z); }
__device__ __forceinline__ f3 f3mul(f3 a, f3 b) { return F3(a.x * b.x, a.y * b.y, a.z * b.z); }
__device__ __forceinline__ f3 f3muls(f3 a, float s) { return F3(a.x * s, a.y * s, a.z * s); }
__device__ __forceinline__ f3 f3fma(f3 a, f3 b, f3 c) {
  return F3(fmaf(a.x, b.x, c.x), fmaf(a.y, b.y, c.y), fmaf(a.z, b.z, c.z));
}
__device__ __forceinline__ f3 f3fmas(float a, f3 b, f3 c) {
  return F3(fmaf(a, b.x, c.x), fmaf(a, b.y, c.y), fmaf(a, b.z, c.z));
}
__device__ __forceinline__ f3 f3rsq(f3 a) {
  return F3(fast_rsqf(a.x), fast_rsqf(a.y), fast_rsqf(a.z));
}
__device__ __forceinline__ f3 f3abs(f3 a) { return F3(fabsf(a.x), fabsf(a.y), fabsf(a.z)); }
__device__ __forceinline__ f3 f3maxs(f3 a, float s) {
  return F3(fmaxf(a.x, s), fmaxf(a.y, s), fmaxf(a.z, s));
}
__device__ __forceinline__ f3 f3log(f3 a) {
  return F3(fast_logf(fmaxf(a.x, EPSV)), fast_logf(fmaxf(a.y, EPSV)),
            fast_logf(fmaxf(a.z, EPSV)));
}
__device__ __forceinline__ f3 f3neg(f3 a) { return F3(-a.x, -a.y, -a.z); }
__device__ __forceinline__ float sgnx1(float mag, float sgn) {
  return __int_as_float(__float_as_int(mag) ^ (__float_as_int(sgn) & 0x80000000));
}
__device__ __forceinline__ f3 f3sgnx(f3 mag, f3 sgn) {
  return F3(sgnx1(mag.x, sgn.x), sgnx1(mag.y, sgn.y), sgnx1(mag.z, sgn.z));
}
__device__ __forceinline__ f3 f3selp(f3 r2, f3 p) {  // (r2<=1e-30) ? 1 : p
  return F3(r2.x <= 1e-30f ? 1.0f : p.x, r2.y <= 1e-30f ? 1.0f : p.y,
            r2.z <= 1e-30f ? 1.0f : p.z);
}

// 2x2 rotation of the (P,Q) pair by (c_, s_, ns_) from enclosing JROT scope.
#define ROTP_(P, Q)                                   \
  { f3 p0_ = P, q0_ = Q;                              \
    P = f3fma(c_, p0_, f3mul(ns_, q0_));              \
    Q = f3fma(s_, p0_, f3mul(c_, q0_)); }

// Givens rotation (p,q), short-critical-path form (HW-verified R5/R10/R11:
// absmax identical to reference-form). Componentwise over the f3 triple.
#define JROT(APP, AQQ, APQ, AK1P, AK1Q, AK2P, AK2Q,                         \
             VP0, VQ0, VP1, VQ1, VP2, VQ2, VP3, VQ3)                        \
  do {                                                                      \
    f3 aa_ = APQ;                                                           \
    f3 d_ = f3sub(AQQ, APP);                                                \
    f3 a2_ = f3add(aa_, aa_);                                               \
    f3 r2_ = f3fma(d_, d_, f3mul(a2_, a2_));                                \
    f3 h_ = f3rsq(f3maxs(r2_, 1e-30f));                                     \
    f3 p_ = f3selp(r2_, f3mul(f3abs(d_), h_));                              \
    f3 q_ = f3fmas(2.0f, p_, f3rep(2.0f));                                  \
    f3 ri_ = f3rsq(q_);                                                     \
    f3 c_ = f3mul(q_, f3muls(ri_, 0.5f));                                   \
    f3 n_ = f3sgnx(f3mul(a2_, h_), d_);                                     \
    f3 s_ = f3mul(n_, ri_);                                                 \
    f3 ns_ = f3neg(s_);                                                     \
    f3 t_ = f3mul(f3add(n_, n_), f3mul(ri_, ri_));                          \
    f3 ta_ = f3mul(t_, aa_);                                                \
    APP = f3sub(APP, ta_);                                                  \
    AQQ = f3add(AQQ, ta_);                                                  \
    APQ = f3rep(0.0f);                                                      \
    ROTP_(AK1P, AK1Q)                                                       \
    ROTP_(AK2P, AK2Q)                                                       \
    ROTP_(VP0, VQ0)                                                         \
    ROTP_(VP1, VQ1)                                                         \
    ROTP_(VP2, VQ2)                                                         \
    ROTP_(VP3, VQ3)                                                         \
  } while (0)

// A upper-tri idx: (0,0)=0 (0,1)=1 (0,2)=2 (0,3)=3 (1,1)=4 (1,2)=5 (1,3)=6
// (2,2)=7 (2,3)=8 (3,3)=9.  V[i*4+j] = V_ij. Compile-time indices only.
#define ROT_01 JROT(A[0], A[4], A[1], A[2], A[5], A[3], A[6],               \
                    V[0], V[1], V[4], V[5], V[8], V[9], V[12], V[13])
#define ROT_02 JROT(A[0], A[7], A[2], A[1], A[5], A[3], A[8],               \
                    V[0], V[2], V[4], V[6], V[8], V[10], V[12], V[14])
#define ROT_03 JROT(A[0], A[9], A[3], A[1], A[6], A[2], A[8],               \
                    V[0], V[3], V[4], V[7], V[8], V[11], V[12], V[15])
#define ROT_12 JROT(A[4], A[7], A[5], A[1], A[2], A[6], A[8],               \
                    V[1], V[2], V[5], V[6], V[9], V[10], V[13], V[14])
#define ROT_13 JROT(A[4], A[9], A[6], A[1], A[3], A[5], A[8],               \
                    V[1], V[3], V[5], V[7], V[9], V[11], V[13], V[15])
#define ROT_23 JROT(A[7], A[9], A[8], A[2], A[3], A[5], A[6],               \
                    V[2], V[3], V[6], V[7], V[10], V[11], V[14], V[15])

__global__ __launch_bounds__(256, 4) void TangentSpaceLayer_64141041598486_kernel(
    const float* __restrict__ x, float* __restrict__ out, int B) {
  __shared__ __align__(16) float so[BT * 10];  // 10 KiB, reused for 3 rounds
  const int t = threadIdx.x;
  const int base = blockIdx.x * MPB;
  const int i0 = min(base + t, B - 1);
  const int i1 = min(base + BT + t, B - 1);
  const int i2 = min(base + 2 * BT + t, B - 1);  // clamped tail, discarded

  const float4* p0 = (const float4*)(x + (size_t)i0 * 16);
  const float4* p1 = (const float4*)(x + (size_t)i1 * 16);
  const float4* p2 = (const float4*)(x + (size_t)i2 * 16);
  float4 a0 = p0[0], a1 = p0[1], a2 = p0[2], a3 = p0[3];
  float4 b0 = p1[0], b1 = p1[1], b2 = p1[2], b3 = p1[3];
  float4 c0 = p2[0], c1 = p2[1], c2 = p2[2], c3 = p2[3];

  f3 A[10], V[16];
  // symmetrize + EPS*I, three matrices packed per component
  A[0] = F3(a0.x + EPSV, b0.x + EPSV, c0.x + EPSV);
  A[1] = F3(0.5f * (a0.y + a1.x), 0.5f * (b0.y + b1.x), 0.5f * (c0.y + c1.x));
  A[2] = F3(0.5f * (a0.z + a2.x), 0.5f * (b0.z + b2.x), 0.5f * (c0.z + c2.x));
  A[3] = F3(0.5f * (a0.w + a3.x), 0.5f * (b0.w + b3.x), 0.5f * (c0.w + c3.x));
  A[4] = F3(a1.y + EPSV, b1.y + EPSV, c1.y + EPSV);
  A[5] = F3(0.5f * (a1.z + a2.y), 0.5f * (b1.z + b2.y), 0.5f * (c1.z + c2.y));
  A[6] = F3(0.5f * (a1.w + a3.y), 0.5f * (b1.w + b3.y), 0.5f * (c1.w + c3.y));
  A[7] = F3(a2.z + EPSV, b2.z + EPSV, c2.z + EPSV);
  A[8] = F3(0.5f * (a2.w + a3.z), 0.5f * (b2.w + b3.z), 0.5f * (c2.w + c3.z));
  A[9] = F3(a3.w + EPSV, b3.w + EPSV, c3.w + EPSV);
#pragma unroll
  for (int i = 0; i < 16; ++i) V[i] = f3rep((i % 5 == 0) ? 1.0f : 0.0f);

#pragma unroll 1
  for (int sweep = 0; sweep < NSWEEP; ++sweep) {
    ROT_01; ROT_02; ROT_03; ROT_12; ROT_13; ROT_23;
  }

  // epilogue: logm reconstruction, three matrices per component
  f3 lw0 = f3log(A[0]);
  f3 lw1 = f3log(A[4]);
  f3 lw2 = f3log(A[7]);
  f3 lw3 = f3log(A[9]);

  f3 w00 = f3mul(V[0], lw0),  w01 = f3mul(V[1], lw1),
     w02 = f3mul(V[2], lw2),  w03 = f3mul(V[3], lw3);
  f3 w10 = f3mul(V[4], lw0),  w11 = f3mul(V[5], lw1),
     w12 = f3mul(V[6], lw2),  w13 = f3mul(V[7], lw3);
  f3 w20 = f3mul(V[8], lw0),  w21 = f3mul(V[9], lw1),
     w22 = f3mul(V[10], lw2), w23 = f3mul(V[11], lw3);
  f3 w30 = f3mul(V[12], lw0), w31 = f3mul(V[13], lw1),
     w32 = f3mul(V[14], lw2), w33 = f3mul(V[15], lw3);

  f3 o[10];
  o[0] = f3fma(w00, V[0],  f3fma(w01, V[1],  f3fma(w02, V[2],  f3mul(w03, V[3]))));
  o[1] = f3fma(w00, V[4],  f3fma(w01, V[5],  f3fma(w02, V[6],  f3mul(w03, V[7]))));
  o[2] = f3fma(w00, V[8],  f3fma(w01, V[9],  f3fma(w02, V[10], f3mul(w03, V[11]))));
  o[3] = f3fma(w00, V[12], f3fma(w01, V[13], f3fma(w02, V[14], f3mul(w03, V[15]))));
  o[4] = f3fma(w10, V[4],  f3fma(w11, V[5],  f3fma(w12, V[6],  f3mul(w13, V[7]))));
  o[5] = f3fma(w10, V[8],  f3fma(w11, V[9],  f3fma(w12, V[10], f3mul(w13, V[11]))));
  o[6] = f3fma(w10, V[12], f3fma(w11, V[13], f3fma(w12, V[14], f3mul(w13, V[15]))));
  o[7] = f3fma(w20, V[8],  f3fma(w21, V[9],  f3fma(w22, V[10], f3mul(w23, V[11]))));
  o[8] = f3fma(w20, V[12], f3fma(w21, V[13], f3fma(w22, V[14], f3mul(w23, V[15]))));
  o[9] = f3fma(w30, V[12], f3fma(w31, V[13], f3fma(w32, V[14], f3mul(w33, V[15]))));

  // three sync-guarded store rounds through the shared 10 KiB buffer.
  // COMP picked at compile time per round (rule #20: no runtime f3 indexing).
#define STORE_ROUND(COMP, H)                                                \
  {                                                                         \
    float* sp = so + t * 10;                                                \
    _Pragma("unroll")                                                       \
    for (int i = 0; i < 10; ++i) sp[i] = o[i].COMP;                         \
    __syncthreads();                                                        \
    const int mbase = base + (H) * BT;                                      \
    const int valid = min(BT, B - mbase);                                   \
    const int nf = valid * 10;                                              \
    const int n4 = nf >> 2;                                                 \
    float* obase = out + (size_t)mbase * 10;                                \
    const float4* s4 = (const float4*)so;                                   \
    float4* o4 = (float4*)obase;                                            \
    for (int i = t; i < n4; i += BT) o4[i] = s4[i];                         \
    for (int i = n4 * 4 + t; i < nf; i += BT) obase[i] = so[i];             \
    __syncthreads();                                                        \
  }

  STORE_ROUND(x, 0)
  STORE_ROUND(y, 1)
  STORE_ROUND(z, 2)
#undef STORE_ROUND
}

extern "C" void kernel_launch(void* const* d_in, const int* in_sizes, int n_in,
                              void* d_out, int out_size, void* d_ws, size_t ws_size,
                              hipStream_t stream) {
  const float* x = (const float*)d_in[0];
  float* out = (float*)d_out;
  const int B = in_sizes[0] / 16;
  const int blocks = (B + MPB - 1) / MPB;
  hipLaunchKernelGGL(TangentSpaceLayer_64141041598486_kernel, dim3(blocks),
                     dim3(BT), 0, stream, x, out, B);
}

// Round 16
// 116.317 us; speedup vs baseline: 1.0029x; 1.0029x over previous
//
#include <hip/hip_runtime.h>
#include <math.h>

#ifndef NSWEEP
#define NSWEEP 4   // HARD MINIMUM (R12 measured): 3 sweeps -> absmax 0.14 FAIL,
                   // 4 sweeps -> 0.0156 pass (bf16-quantization floor, 3x margin).
#endif

#define EPSV 1e-8f
#define BT 256       // threads per block
#define MPB (2 * BT) // 2 matrices per thread, SoA-paired (f2: R11 measured best;
                     // f3/f4 dead: compiler hard-caps VGPR=64 -> spills, R14)

__device__ __forceinline__ float fast_rsqf(float x) {
#if __has_builtin(__builtin_amdgcn_rsqf)
  return __builtin_amdgcn_rsqf(x);
#else
  return rsqrtf(x);
#endif
}
__device__ __forceinline__ float fast_logf(float x) {
#if __has_builtin(__builtin_amdgcn_logf)
  return __builtin_amdgcn_logf(x) * 0.6931471805599453f;  // v_log_f32 is log2
#else
  return logf(x);
#endif
}

// f2 = two independent matrices' scalars, forced instruction-pairing (R11 HW-
// verified: beats serial NM=2/NM=3). Fits the compiler's rigid 64-VGPR budget.
struct f2 { float x, y; };
__device__ __forceinline__ f2 F2(float a, float b) { f2 r; r.x = a; r.y = b; return r; }
__device__ __forceinline__ f2 f2add(f2 a, f2 b) { return F2(a.x + b.x, a.y + b.y); }
__device__ __forceinline__ f2 f2sub(f2 a, f2 b) { return F2(a.x - b.x, a.y - b.y); }
__device__ __forceinline__ f2 f2mul(f2 a, f2 b) { return F2(a.x * b.x, a.y * b.y); }
__device__ __forceinline__ f2 f2muls(f2 a, float s) { return F2(a.x * s, a.y * s); }
__device__ __forceinline__ f2 f2fma(f2 a, f2 b, f2 c) {
  return F2(fmaf(a.x, b.x, c.x), fmaf(a.y, b.y, c.y));
}
__device__ __forceinline__ f2 f2rsq(f2 a) { return F2(fast_rsqf(a.x), fast_rsqf(a.y)); }
__device__ __forceinline__ f2 f2abs(f2 a) { return F2(fabsf(a.x), fabsf(a.y)); }
__device__ __forceinline__ f2 f2maxs(f2 a, float s) { return F2(fmaxf(a.x, s), fmaxf(a.y, s)); }
__device__ __forceinline__ f2 f2log(f2 a) { return F2(fast_logf(fmaxf(a.x, EPSV)), fast_logf(fmaxf(a.y, EPSV))); }
__device__ __forceinline__ f2 f2neg(f2 a) { return F2(-a.x, -a.y); }
__device__ __forceinline__ f2 f2sgnx(f2 mag, f2 sgn) {  // mag ^ signbit(sgn)
  return F2(__int_as_float(__float_as_int(mag.x) ^ (__float_as_int(sgn.x) & 0x80000000)),
            __int_as_float(__float_as_int(mag.y) ^ (__float_as_int(sgn.y) & 0x80000000)));
}
__device__ __forceinline__ f2 f2selp(f2 r2, f2 p) {  // (r2<=1e-30) ? 1 : p
  return F2(r2.x <= 1e-30f ? 1.0f : p.x, r2.y <= 1e-30f ? 1.0f : p.y);
}

// 2x2 rotation of the (P,Q) pair by (c_, s_, ns_) from enclosing JROT scope.
#define ROTP_(P, Q)                                   \
  { f2 p0_ = P, q0_ = Q;                              \
    P = f2fma(c_, p0_, f2mul(ns_, q0_));              \
    Q = f2fma(s_, p0_, f2mul(c_, q0_)); }

// Givens rotation (p,q), short-critical-path form (HW-verified R5/R10/R11:
// absmax identical to reference-form). Componentwise over the f2 pair.
#define JROT(APP, AQQ, APQ, AK1P, AK1Q, AK2P, AK2Q,                         \
             VP0, VQ0, VP1, VQ1, VP2, VQ2, VP3, VQ3)                        \
  do {                                                                      \
    f2 aa_ = APQ;                                                           \
    f2 d_ = f2sub(AQQ, APP);                                                \
    f2 a2_ = f2add(aa_, aa_);                                               \
    f2 r2_ = f2fma(d_, d_, f2mul(a2_, a2_));                                \
    f2 h_ = f2rsq(f2maxs(r2_, 1e-30f));                                     \
    f2 p_ = f2selp(r2_, f2mul(f2abs(d_), h_));                              \
    f2 q_ = F2(fmaf(2.0f, p_.x, 2.0f), fmaf(2.0f, p_.y, 2.0f));             \
    f2 ri_ = f2rsq(q_);                                                     \
    f2 c_ = f2mul(q_, f2muls(ri_, 0.5f));                                   \
    f2 n_ = f2sgnx(f2mul(a2_, h_), d_);                                     \
    f2 s_ = f2mul(n_, ri_);                                                 \
    f2 ns_ = f2neg(s_);                                                     \
    f2 t_ = f2mul(f2add(n_, n_), f2mul(ri_, ri_));                          \
    f2 ta_ = f2mul(t_, aa_);                                                \
    APP = f2sub(APP, ta_);                                                  \
    AQQ = f2add(AQQ, ta_);                                                  \
    APQ = F2(0.0f, 0.0f);                                                   \
    ROTP_(AK1P, AK1Q)                                                       \
    ROTP_(AK2P, AK2Q)                                                       \
    ROTP_(VP0, VQ0)                                                         \
    ROTP_(VP1, VQ1)                                                         \
    ROTP_(VP2, VQ2)                                                         \
    ROTP_(VP3, VQ3)                                                         \
  } while (0)

// A upper-tri idx: (0,0)=0 (0,1)=1 (0,2)=2 (0,3)=3 (1,1)=4 (1,2)=5 (1,3)=6
// (2,2)=7 (2,3)=8 (3,3)=9.  V[i*4+j] = V_ij. Compile-time indices only.
#define ROT_01 JROT(A[0], A[4], A[1], A[2], A[5], A[3], A[6],               \
                    V[0], V[1], V[4], V[5], V[8], V[9], V[12], V[13])
#define ROT_02 JROT(A[0], A[7], A[2], A[1], A[5], A[3], A[8],               \
                    V[0], V[2], V[4], V[6], V[8], V[10], V[12], V[14])
#define ROT_03 JROT(A[0], A[9], A[3], A[1], A[6], A[2], A[8],               \
                    V[0], V[3], V[4], V[7], V[8], V[11], V[12], V[15])
#define ROT_12 JROT(A[4], A[7], A[5], A[1], A[2], A[6], A[8],               \
                    V[1], V[2], V[5], V[6], V[9], V[10], V[13], V[14])
#define ROT_13 JROT(A[4], A[9], A[6], A[1], A[3], A[5], A[8],               \
                    V[1], V[3], V[5], V[7], V[9], V[11], V[13], V[15])
#define ROT_23 JROT(A[7], A[9], A[8], A[2], A[3], A[5], A[6],               \
                    V[2], V[3], V[6], V[7], V[10], V[11], V[14], V[15])

__global__ __launch_bounds__(256, 4) void TangentSpaceLayer_64141041598486_kernel(
    const float* __restrict__ x, float* __restrict__ out, int B) {
  __shared__ __align__(16) float so[BT * 10];  // 10 KiB, reused for 2 halves
  const int t = threadIdx.x;
  const int base = blockIdx.x * MPB;
  const int i0 = min(base + t, B - 1);        // x-lane matrix
  const int i1 = min(base + BT + t, B - 1);   // y-lane matrix (clamped tail)

  const float4* p0 = (const float4*)(x + (size_t)i0 * 16);
  const float4* p1 = (const float4*)(x + (size_t)i1 * 16);
  float4 a0 = p0[0], a1 = p0[1], a2 = p0[2], a3 = p0[3];
  float4 b0 = p1[0], b1 = p1[1], b2 = p1[2], b3 = p1[3];

  f2 A[10], V[16];
  // symmetrize + EPS*I, both matrices packed per component
  A[0] = F2(a0.x + EPSV, b0.x + EPSV);
  A[1] = F2(0.5f * (a0.y + a1.x), 0.5f * (b0.y + b1.x));
  A[2] = F2(0.5f * (a0.z + a2.x), 0.5f * (b0.z + b2.x));
  A[3] = F2(0.5f * (a0.w + a3.x), 0.5f * (b0.w + b3.x));
  A[4] = F2(a1.y + EPSV, b1.y + EPSV);
  A[5] = F2(0.5f * (a1.z + a2.y), 0.5f * (b1.z + b2.y));
  A[6] = F2(0.5f * (a1.w + a3.y), 0.5f * (b1.w + b3.y));
  A[7] = F2(a2.z + EPSV, b2.z + EPSV);
  A[8] = F2(0.5f * (a2.w + a3.z), 0.5f * (b2.w + b3.z));
  A[9] = F2(a3.w + EPSV, b3.w + EPSV);
#pragma unroll
  for (int i = 0; i < 16; ++i) V[i] = F2((i % 5 == 0) ? 1.0f : 0.0f,
                                         (i % 5 == 0) ? 1.0f : 0.0f);

  // FULL unroll (vs R11's `#pragma unroll 1`): lets the compiler constant-fold
  // V=I through sweep 1 (rotation (0,1)'s V-update becomes register renames,
  // later sweep-1 V-rotations fold to ~half cost). Exact arithmetic -> absmax
  // must stay bit-identical at 0.015625.
#pragma unroll
  for (int sweep = 0; sweep < NSWEEP; ++sweep) {
    ROT_01; ROT_02; ROT_03; ROT_12; ROT_13; ROT_23;
  }

  // epilogue: logm reconstruction, both matrices per component
  f2 lw0 = f2log(A[0]);
  f2 lw1 = f2log(A[4]);
  f2 lw2 = f2log(A[7]);
  f2 lw3 = f2log(A[9]);

  f2 w00 = f2mul(V[0], lw0),  w01 = f2mul(V[1], lw1),
     w02 = f2mul(V[2], lw2),  w03 = f2mul(V[3], lw3);
  f2 w10 = f2mul(V[4], lw0),  w11 = f2mul(V[5], lw1),
     w12 = f2mul(V[6], lw2),  w13 = f2mul(V[7], lw3);
  f2 w20 = f2mul(V[8], lw0),  w21 = f2mul(V[9], lw1),
     w22 = f2mul(V[10], lw2), w23 = f2mul(V[11], lw3);
  f2 w30 = f2mul(V[12], lw0), w31 = f2mul(V[13], lw1),
     w32 = f2mul(V[14], lw2), w33 = f2mul(V[15], lw3);

  f2 o[10];
  o[0] = f2fma(w00, V[0],  f2fma(w01, V[1],  f2fma(w02, V[2],  f2mul(w03, V[3]))));
  o[1] = f2fma(w00, V[4],  f2fma(w01, V[5],  f2fma(w02, V[6],  f2mul(w03, V[7]))));
  o[2] = f2fma(w00, V[8],  f2fma(w01, V[9],  f2fma(w02, V[10], f2mul(w03, V[11]))));
  o[3] = f2fma(w00, V[12], f2fma(w01, V[13], f2fma(w02, V[14], f2mul(w03, V[15]))));
  o[4] = f2fma(w10, V[4],  f2fma(w11, V[5],  f2fma(w12, V[6],  f2mul(w13, V[7]))));
  o[5] = f2fma(w10, V[8],  f2fma(w11, V[9],  f2fma(w12, V[10], f2mul(w13, V[11]))));
  o[6] = f2fma(w10, V[12], f2fma(w11, V[13], f2fma(w12, V[14], f2mul(w13, V[15]))));
  o[7] = f2fma(w20, V[8],  f2fma(w21, V[9],  f2fma(w22, V[10], f2mul(w23, V[11]))));
  o[8] = f2fma(w20, V[12], f2fma(w21, V[13], f2fma(w22, V[14], f2mul(w23, V[15]))));
  o[9] = f2fma(w30, V[12], f2fma(w31, V[13], f2fma(w32, V[14], f2mul(w33, V[15]))));

  // two sync-guarded store rounds through the shared 10 KiB buffer
#pragma unroll 1
  for (int half = 0; half < 2; ++half) {
    float* sp = so + t * 10;
#pragma unroll
    for (int i = 0; i < 10; ++i) sp[i] = half ? o[i].y : o[i].x;

    __syncthreads();

    const int mbase = base + half * BT;
    const int valid = min(BT, B - mbase);
    const int nf = valid * 10;
    const int n4 = nf >> 2;
    float* obase = out + (size_t)mbase * 10;
    const float4* s4 = (const float4*)so;
    float4* o4 = (float4*)obase;
    for (int i = t; i < n4; i += BT) o4[i] = s4[i];
    for (int i = n4 * 4 + t; i < nf; i += BT) obase[i] = so[i];

    __syncthreads();  // buffer reuse guard
  }
}

extern "C" void kernel_launch(void* const* d_in, const int* in_sizes, int n_in,
                              void* d_out, int out_size, void* d_ws, size_t ws_size,
                              hipStream_t stream) {
  const float* x = (const float*)d_in[0];
  float* out = (float*)d_out;
  const int B = in_sizes[0] / 16;
  const int blocks = (B + MPB - 1) / MPB;
  hipLaunchKernelGGL(TangentSpaceLayer_64141041598486_kernel, dim3(blocks),
                     dim3(BT), 0, stream, x, out, B);
}